// Round 10
// baseline (122.907 us; speedup 1.0000x reference)
//
#include <hip/hip_runtime.h>
#include <hip/hip_bf16.h>
#include <hip/hip_cooperative_groups.h>

namespace cg = cooperative_groups;

// out[b,n] = sum_k x[b,k] * weight[indices[n],k]
// M=64, N=4403, K=4096, fp32 in/out.
// R10: R5/R6/R8/R9 all ~33us despite 4 different GEMM structures -> the
// invariant is the 3-dispatch pipeline (2 gaps + cvt_x round-trip + reduce).
// Fuse EVERYTHING into one cooperative kernel:
//   phase1: (nb,kb) work items strided over grid; R6's stage(bf16,XOR-swz)
//           + compute; x loaded f32 + cvt in-register (no cvt_x kernel)
//   grid.sync()
//   phase2: distributed reduction of 8 K-partials -> out

#define HIDDEN 4096
#define KSPLIT 8
#define KCHUNK (HIDDEN / KSPLIT)   // 512
#define KSTEPS (KCHUNK / 32)       // 16
#define BATCH  64
#define NTILE  32
#define NTILES 138                 // ceil(4403/32)
#define WORK   (NTILES * KSPLIT)   // 1104

using short8 = __attribute__((ext_vector_type(8))) short;
using f32x4  = __attribute__((ext_vector_type(4))) float;

__device__ __forceinline__ short f2bf(float f) {
    __bf16 h = (__bf16)f;                 // pairs into v_cvt_pk_bf16_f32
    return __builtin_bit_cast(short, h);
}

__device__ __forceinline__ short8 cvt8(const f32x4& lo, const f32x4& hi) {
    short8 r;
    r[0] = f2bf(lo[0]); r[1] = f2bf(lo[1]); r[2] = f2bf(lo[2]); r[3] = f2bf(lo[3]);
    r[4] = f2bf(hi[0]); r[5] = f2bf(hi[1]); r[6] = f2bf(hi[2]); r[7] = f2bf(hi[3]);
    return r;
}

__global__ __launch_bounds__(256, 4) void fused_up(
    const float* __restrict__ weight,   // [11008, 4096] f32
    const float* __restrict__ x,        // [64, 4096] f32
    const int*   __restrict__ indices,  // [R]
    float*       __restrict__ part,     // ws: [KSPLIT, 64, R] partials
    float*       __restrict__ out,      // [64, R]
    int R)
{
    __shared__ unsigned short wlds[NTILE * KCHUNK];   // 32 KB, XOR-swizzled

    const int t    = threadIdx.x;
    const int lane = t & 63;
    const int wave = t >> 6;
    const int nl   = lane & 15;
    const int kg   = lane >> 4;
    const int sr   = t >> 3;           // staging row 0..31
    const int sc   = t & 7;            // staging col-group 0..7

    // ---- phase 1: GEMM over (nb,kb) work items -----------------------------
    for (int wk = blockIdx.x; wk < WORK; wk += gridDim.x) {
        const int kb = wk / NTILES;
        const int nb = wk - kb * NTILES;
        const int k0 = kb * KCHUNK;

        __syncthreads();   // previous item's LDS readers are done

        // stage weight tile rows nb*32..+31, cols k0..k0+511, bf16 + XOR swz
        {
            const int n    = nb * NTILE + sr;
            const int wrow = indices[n < R ? n : R - 1];
            const float* src = weight + (size_t)wrow * HIDDEN + k0 + sc * 8;
            char* ldsrow = (char*)wlds + sr * (KCHUNK * 2);
            const unsigned int swz = (unsigned int)((sr & 7) << 4);
#pragma unroll
            for (int s = 0; s < 8; ++s) {
                f32x4 v0 = *(const f32x4*)(src + s * 64);
                f32x4 v1 = *(const f32x4*)(src + s * 64 + 4);
                short8 h = cvt8(v0, v1);
                *(short8*)(ldsrow + ((unsigned int)(sc * 16 + s * 128) ^ swz)) = h;
            }
        }
        __syncthreads();

        // compute: per K-step {2 x-loads f32x4 + cvt, 2 swizzled ds_read + 2 MFMA}
        const float* xrow = x + (size_t)(wave * 16 + nl) * HIDDEN + k0 + kg * 8;
        f32x4 acc0 = {0.f,0.f,0.f,0.f}, acc1 = {0.f,0.f,0.f,0.f};

#pragma unroll
        for (int ks = 0; ks < KSTEPS; ++ks) {
            f32x4 xa = *(const f32x4*)(xrow + ks * 32);
            f32x4 xb = *(const f32x4*)(xrow + ks * 32 + 4);
            short8 a = cvt8(xa, xb);
#pragma unroll
            for (int nf = 0; nf < 2; ++nf) {
                const int rr = nf * 16 + nl;
                const unsigned int bc =
                    (unsigned int)(ks * 64 + kg * 16) ^ (unsigned int)((rr & 7) << 4);
                short8 b = *(const short8*)((const char*)wlds + rr * (KCHUNK * 2) + bc);
                f32x4& acc = nf == 0 ? acc0 : acc1;
                acc = __builtin_amdgcn_mfma_f32_16x16x32_bf16(a, b, acc, 0, 0, 0);
            }
        }

        // store partials: C/D col = nl (n), row = kg*4 + r
        float* p = part + (size_t)kb * BATCH * R;
        f32x4 accs[2] = {acc0, acc1};
#pragma unroll
        for (int nf = 0; nf < 2; ++nf) {
            const int nn = nb * NTILE + nf * 16 + nl;
            if (nn < R) {
#pragma unroll
                for (int r = 0; r < 4; ++r) {
                    const int brow = wave * 16 + kg * 4 + r;
                    p[(size_t)brow * R + nn] = accs[nf][r];
                }
            }
        }
    }

    // ---- phase 2: reduce 8 partials -> out ---------------------------------
    cg::this_grid().sync();

    const int n4 = (BATCH * R) / 4;        // 70448
    const int T  = gridDim.x * 256;
    const f32x4* pw = (const f32x4*)part;
    for (int i = blockIdx.x * 256 + t; i < n4; i += T) {
        f32x4 s = pw[i];
#pragma unroll
        for (int kb = 1; kb < KSPLIT; ++kb) {
            f32x4 v = pw[(size_t)kb * n4 + i];
            s[0] += v[0]; s[1] += v[1]; s[2] += v[2]; s[3] += v[3];
        }
        ((f32x4*)out)[i] = s;
    }
}

extern "C" void kernel_launch(void* const* d_in, const int* in_sizes, int n_in,
                              void* d_out, int out_size, void* d_ws, size_t ws_size,
                              hipStream_t stream) {
    const float* x       = (const float*)d_in[0];
    const float* weight  = (const float*)d_in[1];
    const int*   indices = (const int*)d_in[2];
    float*       out     = (float*)d_out;
    float*       part    = (float*)d_ws;
    int          R       = in_sizes[2];    // 4403

    int perCU = 0;
    if (hipOccupancyMaxActiveBlocksPerMultiprocessor(&perCU, fused_up, 256, 0)
            != hipSuccess || perCU <= 0)
        perCU = 2;                         // conservative fallback
    int G = perCU * 256;                   // 256 CUs on MI355X
    if (G > WORK) G = WORK;

    void* args[] = {(void*)&weight, (void*)&x, (void*)&indices,
                    (void*)&part, (void*)&out, (void*)&R};
    hipLaunchCooperativeKernel((void*)fused_up, dim3(G), dim3(256), args, 0, stream);
}

// Round 11
// 42.850 us; speedup vs baseline: 2.8683x; 2.8683x over previous
//
#include <hip/hip_runtime.h>
#include <hip/hip_bf16.h>

// out[b,n] = sum_k x[b,k] * weight[indices[n],k]
// M=64, N=4403, K=4096, fp32 in/out.
// R11: every prior GEMM burst-staged (stage -> barrier(vmcnt0) -> compute)
// -> ~50% load-issue duty cycle -> ~7 TB/s realized L3. Fix: item-paired
// double buffer with global_load_lds (zero register cost in flight):
//   block = (nb, q): items kb=2q and 2q+1 through 2x32KB f32 LDS buffers.
//   stage(buf0,kb0); preload a-frags(both); sync; stage(buf1,kb1) flies
//   under compute0; sync; compute1. Plain __syncthreads only (no counted
//   vmcnt -> no race risk). cvt_x + KSPLIT=8 partials + reduce as R6.

#define HIDDEN 4096
#define KSPLIT 8
#define KCHUNK (HIDDEN / KSPLIT)   // 512
#define KSTEPS (KCHUNK / 32)       // 16
#define BATCH  64
#define NTILE  16
#define NTILES 276                 // ceil(4403/16)
#define XBF_OFF (16u << 20)        // byte offset of x_bf16 inside ws

using short8 = __attribute__((ext_vector_type(8))) short;
using f32x4  = __attribute__((ext_vector_type(4))) float;

typedef const void __attribute__((address_space(1))) gvoid;
typedef void __attribute__((address_space(3))) svoid;

__device__ __forceinline__ short f2bf(float f) {
    __bf16 h = (__bf16)f;                 // pairs into v_cvt_pk_bf16_f32
    return __builtin_bit_cast(short, h);
}

__device__ __forceinline__ short8 cvt8(const f32x4& lo, const f32x4& hi) {
    short8 r;
    r[0] = f2bf(lo[0]); r[1] = f2bf(lo[1]); r[2] = f2bf(lo[2]); r[3] = f2bf(lo[3]);
    r[4] = f2bf(hi[0]); r[5] = f2bf(hi[1]); r[6] = f2bf(hi[2]); r[7] = f2bf(hi[3]);
    return r;
}

// ---- k0: convert x to bf16 -------------------------------------------------
__global__ __launch_bounds__(256) void cvt_x(
    const float* __restrict__ x, unsigned short* __restrict__ xbf)
{
    const int i = (blockIdx.x * 256 + threadIdx.x) * 8;
    f32x4 a = *(const f32x4*)(x + i);
    f32x4 b = *(const f32x4*)(x + i + 4);
    *(short8*)(xbf + i) = cvt8(a, b);
}

// ---- k1: gathered GEMM, dbuf gload_lds staging, 2 items per block ----------
__global__ __launch_bounds__(256, 2) void gather_gemm(
    const float*          __restrict__ weight,   // [11008, 4096] f32
    const unsigned short* __restrict__ xbf,      // [64, 4096] bf16
    const int*            __restrict__ indices,  // [R]
    float*                __restrict__ ws,       // [KSPLIT, 64, R] partials
    int R)
{
    __shared__ float wlds[2][NTILE * KCHUNK];   // 2 x 32 KB f32

    const int t    = threadIdx.x;
    const int lane = t & 63;
    const int wave = t >> 6;
    const int nl   = lane & 15;
    const int kg   = lane >> 4;
    const int nb   = blockIdx.x;        // N-tile of 16
    const int kb0  = blockIdx.y * 2;    // items kb0, kb0+1
    const int kb1  = kb0 + 1;

    // ---- staging helper: buffer buf <- weight rows, K-chunk kb -------------
    // wave w stages rows 4w..4w+3; 8 gload_lds(16B)/thread; LDS dest linear
    // (wave-uniform base + lane*16); global src pre-swizzled byte ^ ((r&7)<<5)
    // (involution within 256B groups) so consumer reads conflict-spread.
#define STAGE(buf, kb)                                                         \
    {                                                                          \
        _Pragma("unroll")                                                      \
        for (int j = 0; j < 8; ++j) {                                          \
            const int r = 4 * wave + (j >> 1);                                 \
            const int h = j & 1;                                               \
            const int n = nb * NTILE + r;                                      \
            const int wrow = indices[n < R ? n : R - 1];                       \
            const char* rowp =                                                 \
                (const char*)(weight + (size_t)wrow * HIDDEN + (kb) * KCHUNK); \
            const unsigned int srcoff =                                        \
                ((unsigned int)(h * 1024 + lane * 16)) ^                       \
                ((unsigned int)((r & 7) << 5));                                \
            __builtin_amdgcn_global_load_lds(                                  \
                (gvoid*)(rowp + srcoff),                                       \
                (svoid*)((char*)wlds[buf] + r * 2048 + h * 1024), 16, 0, 0);   \
        }                                                                      \
    }

    // ---- compute helper: consume buffer buf with a-frags afr ---------------
#define COMPUTE(buf, afr, acc)                                                 \
    {                                                                          \
        _Pragma("unroll")                                                      \
        for (int ks = 0; ks < KSTEPS; ++ks) {                                  \
            const unsigned int g0 = (unsigned int)(ks * 128 + kg * 32);        \
            const unsigned int off = g0 ^ ((unsigned int)((nl & 7) << 5));     \
            const char* rowbase = (const char*)wlds[buf] + nl * 2048;          \
            f32x4 w0 = *(const f32x4*)(rowbase + off);                         \
            f32x4 w1 = *(const f32x4*)(rowbase + off + 16);                    \
            short8 b = cvt8(w0, w1);                                           \
            acc = __builtin_amdgcn_mfma_f32_16x16x32_bf16(afr[ks], b, acc,     \
                                                          0, 0, 0);            \
        }                                                                      \
    }

    // ---- store helper: C/D col = nl (n), row = kg*4 + r (batch) ------------
#define STORE(kb, acc)                                                         \
    {                                                                          \
        const int nn = nb * NTILE + nl;                                        \
        if (nn < R) {                                                          \
            float* p = ws + (size_t)(kb) * BATCH * R;                          \
            _Pragma("unroll")                                                  \
            for (int r = 0; r < 4; ++r) {                                      \
                const int brow = wave * 16 + kg * 4 + r;                       \
                p[(size_t)brow * R + nn] = acc[r];                             \
            }                                                                  \
        }                                                                      \
    }

    // stage item0, preload a-frags for BOTH items (all fly together)
    STAGE(0, kb0);

    const unsigned short* xrow =
        xbf + (size_t)(wave * 16 + nl) * HIDDEN + kg * 8;
    short8 afrA[KSTEPS], afrB[KSTEPS];
#pragma unroll
    for (int ks = 0; ks < KSTEPS; ++ks)
        afrA[ks] = *(const short8*)(xrow + kb0 * KCHUNK + ks * 32);
#pragma unroll
    for (int ks = 0; ks < KSTEPS; ++ks)
        afrB[ks] = *(const short8*)(xrow + kb1 * KCHUNK + ks * 32);

    __syncthreads();                 // buf0 + a-frags ready

    STAGE(1, kb1);                   // flies under compute0

    f32x4 acc0 = {0.f, 0.f, 0.f, 0.f};
    COMPUTE(0, afrA, acc0);
    STORE(kb0, acc0);

    __syncthreads();                 // buf1 ready (barrier drains vmcnt)

    f32x4 acc1 = {0.f, 0.f, 0.f, 0.f};
    COMPUTE(1, afrB, acc1);
    STORE(kb1, acc1);

#undef STAGE
#undef COMPUTE
#undef STORE
}

// ---- k2: sum KSPLIT partials ----------------------------------------------
__global__ __launch_bounds__(256) void reduce_partials(
    const float* __restrict__ ws, float* __restrict__ out, int n4, int stride4)
{
    const int i = blockIdx.x * blockDim.x + threadIdx.x;
    if (i >= n4) return;
    const f32x4* w = (const f32x4*)ws;
    f32x4 s = w[i];
#pragma unroll
    for (int kb = 1; kb < KSPLIT; ++kb) {
        f32x4 v = w[(size_t)kb * stride4 + i];
        s[0] += v[0]; s[1] += v[1]; s[2] += v[2]; s[3] += v[3];
    }
    ((f32x4*)out)[i] = s;
}

extern "C" void kernel_launch(void* const* d_in, const int* in_sizes, int n_in,
                              void* d_out, int out_size, void* d_ws, size_t ws_size,
                              hipStream_t stream) {
    const float* x       = (const float*)d_in[0];
    const float* weight  = (const float*)d_in[1];
    const int*   indices = (const int*)d_in[2];
    float*       out     = (float*)d_out;
    float*       ws      = (float*)d_ws;
    unsigned short* xbf  = (unsigned short*)((char*)d_ws + XBF_OFF);

    const int R = in_sizes[2];                    // 4403

    cvt_x<<<dim3((BATCH * HIDDEN) / (256 * 8)), dim3(256), 0, stream>>>(x, xbf);
    gather_gemm<<<dim3(NTILES, KSPLIT / 2), dim3(256), 0, stream>>>(
        weight, xbf, indices, ws, R);

    const int n4 = (BATCH * R) / 4;
    reduce_partials<<<dim3((n4 + 255) / 256), dim3(256), 0, stream>>>(ws, out, n4, n4);
}